// Round 1
// baseline (248.247 us; speedup 1.0000x reference)
//
#include <hip/hip_runtime.h>

#define T_SEQ 4096
#define DIM   64
#define NQT   32     // T / 128
#define QTILE 128
#define KTILE 128
#define NBH   32     // B*H

typedef __attribute__((ext_vector_type(8)))  short bhalf8;
typedef __attribute__((ext_vector_type(16))) float floatx16;

#if __has_builtin(__builtin_amdgcn_exp2f)
#define EXP2F(x) __builtin_amdgcn_exp2f(x)
#else
#define EXP2F(x) exp2f(x)
#endif

// pack two fp32 -> two bf16 (round-half-up) in one v_perm_b32
__device__ __forceinline__ unsigned pk2bf(float a, float b) {
  unsigned ua = __builtin_bit_cast(unsigned, a) + 0x8000u;
  unsigned ub = __builtin_bit_cast(unsigned, b) + 0x8000u;
  return __builtin_amdgcn_perm(ub, ua, 0x07060302u);
}

union FragU { unsigned u[4]; bhalf8 v; };

__global__ __launch_bounds__(256, 2) void fa_fwd(
    const float* __restrict__ Q, const float* __restrict__ K,
    const float* __restrict__ V, float* __restrict__ O) {
  const int tid  = threadIdx.x;
  const int w    = tid >> 6;        // wave 0..3 -> q rows 32w..32w+31
  const int lane = tid & 63;
  const int n    = lane & 31;       // this lane's q row within the wave tile
  const int h    = lane >> 5;       // lane half
  const int bid  = blockIdx.x;
  const int bh   = bid & (NBH - 1);
  const int qt   = (NQT - 1) - (bid >> 5);   // heavy blocks first

  const int base = bh * (T_SEQ * DIM);

  // K tile row-major [kv][d], V tile transposed [d][kv]; bf16, XOR chunk swizzle
  __shared__ __align__(16) unsigned short Kl[KTILE * DIM];
  __shared__ __align__(16) unsigned short Vt[DIM * KTILE];

  // ---- Q fragments (B operand of S^T = K * Q^T), scale = 1/sqrt(D) * log2(e)
  const int qrow = qt * QTILE + w * 32 + n;
  const float cs = 0.125f * 1.44269504088896340736f;
  FragU qf[4];
  {
    const float* qp = Q + base + qrow * DIM + h * 8;
#pragma unroll
    for (int ks = 0; ks < 4; ++ks) {
      float4 a = *reinterpret_cast<const float4*>(qp + 16 * ks);
      float4 b = *reinterpret_cast<const float4*>(qp + 16 * ks + 4);
      qf[ks].u[0] = pk2bf(a.x * cs, a.y * cs);
      qf[ks].u[1] = pk2bf(a.z * cs, a.w * cs);
      qf[ks].u[2] = pk2bf(b.x * cs, b.y * cs);
      qf[ks].u[3] = pk2bf(b.z * cs, b.w * cs);
    }
  }

  floatx16 o0, o1;
#pragma unroll
  for (int i = 0; i < 16; ++i) { o0[i] = 0.f; o1[i] = 0.f; }
  float m_run = -__builtin_inff();
  float s_run = 0.f;

  for (int kt = 0; kt <= qt; ++kt) {
    __syncthreads();
    // ---------- stage K tile ----------
    {
      const float4* kp4 = reinterpret_cast<const float4*>(K + base + kt * (KTILE * DIM));
      float4 kx[8];
#pragma unroll
      for (int c = 0; c < 8; ++c) kx[c] = kp4[tid + 256 * c];
#pragma unroll
      for (int c = 0; c < 8; ++c) {
        int f4 = tid + 256 * c;
        int kv = f4 >> 4;
        int d0 = (f4 & 15) << 2;
        unsigned lo = pk2bf(kx[c].x, kx[c].y);
        unsigned hi = pk2bf(kx[c].z, kx[c].w);
        unsigned long long u64 = (unsigned long long)lo | ((unsigned long long)hi << 32);
        int idx = (kv << 6) | ((((d0 >> 3) ^ (kv & 7)) << 3) | (d0 & 7));
        *reinterpret_cast<unsigned long long*>(&Kl[idx]) = u64;
      }
      // ---------- stage V tile (transposed) ----------
      const int kv0 = (tid & 63) << 1;          // kv pair
      const int db  = (tid >> 6) << 4;          // d base (16 per group)
      const float* vrow = V + base + kt * (KTILE * DIM) + kv0 * DIM + db;
      float4 va[4], vb[4];
#pragma unroll
      for (int sg = 0; sg < 4; ++sg) {
        va[sg] = *reinterpret_cast<const float4*>(vrow + 4 * sg);
        vb[sg] = *reinterpret_cast<const float4*>(vrow + DIM + 4 * sg);
      }
      const float* vaf = reinterpret_cast<const float*>(va);
      const float* vbf = reinterpret_cast<const float*>(vb);
#pragma unroll
      for (int j = 0; j < 16; ++j) {
        int d = db + j;
        unsigned u = pk2bf(vaf[j], vbf[j]);     // low = kv0, high = kv0+1
        int idx = (d << 7) | ((((kv0 >> 3) ^ (d & 15)) << 3) | (kv0 & 7));
        *reinterpret_cast<unsigned*>(&Vt[idx]) = u;
      }
    }
    __syncthreads();

    // ---------- S^T = K * Q^T : 4 tiles of 32kv x 32q ----------
    floatx16 st[4];
#pragma unroll
    for (int tt = 0; tt < 4; ++tt) {
      floatx16 acc;
#pragma unroll
      for (int i = 0; i < 16; ++i) acc[i] = 0.f;
#pragma unroll
      for (int ks = 0; ks < 4; ++ks) {
        const bhalf8 kfrag = *reinterpret_cast<const bhalf8*>(
            &Kl[((32 * tt + n) << 6) | (((2 * ks + h) ^ (n & 7)) << 3)]);
        acc = __builtin_amdgcn_mfma_f32_32x32x16_bf16(kfrag, qf[ks].v, acc, 0, 0, 0);
      }
      st[tt] = acc;
    }

    if (kt == qt) {  // causal mask, diagonal block only
#pragma unroll
      for (int tt = 0; tt < 4; ++tt)
#pragma unroll
        for (int r = 0; r < 16; ++r) {
          int kvloc = 32 * tt + (r & 3) + 8 * (r >> 2) + 4 * h;
          st[tt][r] = (kvloc > 32 * w + n) ? -__builtin_inff() : st[tt][r];
        }
    }

    // ---------- online softmax (per-lane scalars; lane owns one q row) ----------
    float rmax = st[0][0];
#pragma unroll
    for (int tt = 0; tt < 4; ++tt)
#pragma unroll
      for (int r = 0; r < 16; ++r) rmax = fmaxf(rmax, st[tt][r]);
    rmax = fmaxf(rmax, __shfl_xor(rmax, 32, 64));
    const float mnew  = fmaxf(m_run, rmax);
    const float alpha = EXP2F(m_run - mnew);
    m_run = mnew;

    float psum = 0.f;
#pragma unroll
    for (int tt = 0; tt < 4; ++tt)
#pragma unroll
      for (int r = 0; r < 16; ++r) {
        float p = EXP2F(st[tt][r] - mnew);
        st[tt][r] = p;
        psum += p;
      }
    psum += __shfl_xor(psum, 32, 64);
    s_run = s_run * alpha + psum;
#pragma unroll
    for (int i = 0; i < 16; ++i) { o0[i] *= alpha; o1[i] *= alpha; }

    // ---------- P -> bf16 B-fragments (half-swap) and PV MFMAs ----------
#pragma unroll
    for (int tt = 0; tt < 4; ++tt) {
      unsigned pk[8];
#pragma unroll
      for (int g = 0; g < 4; ++g) {
        pk[2 * g]     = pk2bf(st[tt][4 * g],     st[tt][4 * g + 1]);
        pk[2 * g + 1] = pk2bf(st[tt][4 * g + 2], st[tt][4 * g + 3]);
      }
      unsigned e0 = (unsigned)__shfl_xor((int)(h ? pk[0] : pk[2]), 32, 64);
      unsigned e1 = (unsigned)__shfl_xor((int)(h ? pk[1] : pk[3]), 32, 64);
      unsigned e2 = (unsigned)__shfl_xor((int)(h ? pk[4] : pk[6]), 32, 64);
      unsigned e3 = (unsigned)__shfl_xor((int)(h ? pk[5] : pk[7]), 32, 64);
      FragU b0, b1;
      b0.u[0] = h ? e0 : pk[0];
      b0.u[1] = h ? e1 : pk[1];
      b0.u[2] = h ? pk[2] : e0;
      b0.u[3] = h ? pk[3] : e1;
      b1.u[0] = h ? e2 : pk[4];
      b1.u[1] = h ? e3 : pk[5];
      b1.u[2] = h ? pk[6] : e2;
      b1.u[3] = h ? pk[7] : e3;

      const int sw = n & 15;
      const bhalf8 v00 = *reinterpret_cast<const bhalf8*>(
          &Vt[(n << 7) | (((4 * tt + 0 + h) ^ sw) << 3)]);
      const bhalf8 v01 = *reinterpret_cast<const bhalf8*>(
          &Vt[(n << 7) | (((4 * tt + 2 + h) ^ sw) << 3)]);
      const bhalf8 v10 = *reinterpret_cast<const bhalf8*>(
          &Vt[((32 + n) << 7) | (((4 * tt + 0 + h) ^ sw) << 3)]);
      const bhalf8 v11 = *reinterpret_cast<const bhalf8*>(
          &Vt[((32 + n) << 7) | (((4 * tt + 2 + h) ^ sw) << 3)]);
      o0 = __builtin_amdgcn_mfma_f32_32x32x16_bf16(v00, b0.v, o0, 0, 0, 0);
      o0 = __builtin_amdgcn_mfma_f32_32x32x16_bf16(v01, b1.v, o0, 0, 0, 0);
      o1 = __builtin_amdgcn_mfma_f32_32x32x16_bf16(v10, b0.v, o1, 0, 0, 0);
      o1 = __builtin_amdgcn_mfma_f32_32x32x16_bf16(v11, b1.v, o1, 0, 0, 0);
    }
  }

  // ---------- epilogue: normalize + store ----------
  const float inv = 1.0f / s_run;
  float* op = O + base + qrow * DIM;
#pragma unroll
  for (int g = 0; g < 4; ++g) {
    float4 x, y;
    x.x = o0[4 * g] * inv;  x.y = o0[4 * g + 1] * inv;
    x.z = o0[4 * g + 2] * inv;  x.w = o0[4 * g + 3] * inv;
    y.x = o1[4 * g] * inv;  y.y = o1[4 * g + 1] * inv;
    y.z = o1[4 * g + 2] * inv;  y.w = o1[4 * g + 3] * inv;
    *reinterpret_cast<float4*>(op + 8 * g + 4 * h)      = x;   // d-tile 0
    *reinterpret_cast<float4*>(op + 32 + 8 * g + 4 * h) = y;   // d-tile 1
  }
}

extern "C" void kernel_launch(void* const* d_in, const int* in_sizes, int n_in,
                              void* d_out, int out_size, void* d_ws, size_t ws_size,
                              hipStream_t stream) {
  (void)in_sizes; (void)n_in; (void)d_ws; (void)ws_size; (void)out_size;
  const float* Q = (const float*)d_in[0];
  const float* K = (const float*)d_in[1];
  const float* V = (const float*)d_in[2];
  float* O = (float*)d_out;
  fa_fwd<<<dim3(NQT * NBH), dim3(256), 0, stream>>>(Q, K, V, O);
}